// Round 7
// baseline (272.363 us; speedup 1.0000x reference)
//
#include <hip/hip_runtime.h>
#include <hip/hip_bf16.h>
#include <math.h>

typedef unsigned long long u64;
typedef unsigned int u32;

#define C_NUM 80
#define TOPK 1000
#define CAP 2048
#define HB 128
#define STG 32
#define SCORE_THR 0.05f
#define IOU_THR 0.5f
#define GRID_SCAN 256

// correctly-rounded-ish f32 exp via double (matched reference bit-exact rounds 1-6)
__device__ __forceinline__ float exp_cr(float x) {
    return (float)exp((double)x);
}

// Exact f32 replication of reference decode + clip (no FMA contraction).
__device__ __forceinline__ void decode_box(const float* __restrict__ anch,
                                           const float* __restrict__ reg,
                                           int a, float fw, float fh, float4* out) {
#pragma clang fp contract(off)
    float a0 = anch[(size_t)a * 4 + 0], a1 = anch[(size_t)a * 4 + 1];
    float a2 = anch[(size_t)a * 4 + 2], a3 = anch[(size_t)a * 4 + 3];
    float d0 = reg[(size_t)a * 4 + 0], d1 = reg[(size_t)a * 4 + 1];
    float d2 = reg[(size_t)a * 4 + 2], d3 = reg[(size_t)a * 4 + 3];
    float w = a2 - a0, h = a3 - a1;
    float cx = a0 + 0.5f * w, cy = a1 + 0.5f * h;
    float dx = d0 * 0.1f, dy = d1 * 0.1f, dw = d2 * 0.2f, dh = d3 * 0.2f;
    float t1 = dx * w; float pcx = cx + t1;
    float t2 = dy * h; float pcy = cy + t2;
    float pw = exp_cr(dw) * w;
    float ph = exp_cr(dh) * h;
    float x1 = pcx - 0.5f * pw, y1 = pcy - 0.5f * ph;
    float x2 = pcx + 0.5f * pw, y2 = pcy + 0.5f * ph;
    x1 = fminf(fmaxf(x1, 0.0f), fw);
    y1 = fminf(fmaxf(y1, 0.0f), fh);
    x2 = fminf(fmaxf(x2, 0.0f), fw);
    y2 = fminf(fmaxf(y2, 0.0f), fh);
    *out = make_float4(x1, y1, x2, y2);
}

// Per-block private histogram slices; no global atomics at all.
__global__ __launch_bounds__(1024)
void hist_kernel(const float4* __restrict__ cls4, u32* __restrict__ slices, int nvec) {
    __shared__ u32 h[C_NUM * HB];                 // 40 KB
    int tid = threadIdx.x;
    for (int i = tid; i < C_NUM * HB; i += 1024) h[i] = 0u;
    __syncthreads();
    int gid = blockIdx.x * 1024 + tid;
    const int stride = GRID_SCAN * 1024;          // float4 units
    const int dC = (stride * 4) % C_NUM;
    int c0 = (gid * 4) % C_NUM;
    for (int v = gid; v < nvec; v += stride) {
        float4 f = cls4[v];
        float e[4] = {f.x, f.y, f.z, f.w};
        int cc = c0;
#pragma unroll
        for (int k = 0; k < 4; ++k) {
            int t = (((int)__float_as_uint(e[k])) - 0x3F000000) >> 16;
            if (t > 0) {
                t = t > HB - 1 ? HB - 1 : t;
                atomicAdd(&h[cc * HB + t], 1u);   // LDS atomic only
            }
            cc++; if (cc == C_NUM) cc = 0;
        }
        c0 += dC; if (c0 >= C_NUM) c0 -= C_NUM;
    }
    __syncthreads();
    u32* my = slices + (size_t)blockIdx.x * (C_NUM * HB);
    for (int i = tid; i < C_NUM * HB; i += 1024) my[i] = h[i];
}

// Per-class: parallel reduce of 256 slices (8 groups x 128 buckets) -> suffix-sum
// -> threshold bit-edge.
__global__ __launch_bounds__(1024)
void thr_kernel(const u32* __restrict__ slices, u32* __restrict__ thrG) {
    __shared__ u32 part[8][HB];
    __shared__ u32 s[HB];
    __shared__ int bsel;
    int c = blockIdx.x, tid = threadIdx.x;
    int b = tid & (HB - 1), g = tid >> 7;         // 8 groups of 32 slices each
    u32 sum = 0;
    const u32* base = slices + c * HB + b;
    for (int sl = g * 32; sl < g * 32 + 32; ++sl)
        sum += base[(size_t)sl * (C_NUM * HB)];   // lanes read consecutive -> coalesced
    part[g][b] = sum;
    if (tid == 0) bsel = 0;
    __syncthreads();
    if (tid < HB) {
        u32 t = 0;
#pragma unroll
        for (int g2 = 0; g2 < 8; ++g2) t += part[g2][tid];
        s[tid] = t;
    }
    __syncthreads();
    for (int d = 1; d < HB; d <<= 1) {
        u32 v = 0;
        if (tid < HB) v = s[tid] + ((tid + d < HB) ? s[tid + d] : 0u);
        __syncthreads();
        if (tid < HB) s[tid] = v;
        __syncthreads();
    }
    if (tid < HB) {
        u32 me = s[tid];
        u32 nxt = (tid < HB - 1) ? s[tid + 1] : 0u;
        if (me >= (u32)TOPK && (tid == HB - 1 || nxt < (u32)TOPK)) bsel = tid;
    }
    __syncthreads();
    if (tid == 0) {
        int bb = bsel;
        thrG[c] = (bb == 0) ? 0u : (u32)(0x3F000000 + (bb << 16));
    }
}

// Gather with block-local LDS staging; ONE bulk reservation atomic per (class,block).
__global__ __launch_bounds__(1024)
void gather_kernel(const float4* __restrict__ cls4, const u32* __restrict__ thrG,
                   u32* __restrict__ cntG, u64* __restrict__ pool, int nvec) {
    __shared__ int thrS[C_NUM];
    __shared__ u32 lcnt[C_NUM];
    __shared__ u32 lbase[C_NUM];
    __shared__ u64 stage[C_NUM * STG];            // 20 KB
    int tid = threadIdx.x;
    if (tid < C_NUM) { thrS[tid] = (int)thrG[tid]; lcnt[tid] = 0u; }
    __syncthreads();

    int gid = blockIdx.x * 1024 + tid;
    const int stride = GRID_SCAN * 1024;
    const int dA = (stride * 4) / C_NUM;
    const int dC = (stride * 4) % C_NUM;
    int base = gid * 4;
    int aa0 = base / C_NUM;
    int c0 = base - aa0 * C_NUM;
    for (int v = gid; v < nvec; v += stride) {
        float4 f = cls4[v];
        float e[4] = {f.x, f.y, f.z, f.w};
        int cc = c0, aa = aa0;
#pragma unroll
        for (int k = 0; k < 4; ++k) {
            int bits = (int)__float_as_uint(e[k]);
            if (bits >= thrS[cc]) {
                u64 key = ((u64)(u32)bits << 32) | (u64)(u32)(~(u32)aa);
                u32 p = atomicAdd(&lcnt[cc], 1u);             // LDS atomic
                if (p < STG) stage[cc * STG + p] = key;
                else {                                         // rare overflow fallback
                    u32 q = atomicAdd(&cntG[cc], 1u);
                    if (q < CAP) pool[(size_t)cc * CAP + q] = key;
                }
            }
            cc++; if (cc == C_NUM) { cc = 0; aa++; }
        }
        c0 += dC;
        if (c0 >= C_NUM) { c0 -= C_NUM; aa0 += dA + 1; } else aa0 += dA;
    }
    __syncthreads();
    if (tid < C_NUM) {
        u32 nl = lcnt[tid]; if (nl > STG) nl = STG;
        lbase[tid] = nl ? atomicAdd(&cntG[tid], nl) : 0u;      // one atomic per class
        lcnt[tid] = nl;
    }
    __syncthreads();
    for (int i = tid; i < C_NUM * STG; i += 1024) {
        int c = i >> 5, k = i & (STG - 1);
        if ((u32)k < lcnt[c]) {
            u32 q = lbase[c] + (u32)k;
            if (q < CAP) pool[(size_t)c * CAP + q] = stage[i];
        }
    }
}

// Rank-sort spread over all CUs: grid (C_NUM, 8) x 256. Each block loads the
// class pool into LDS (b128 pairs), each thread ranks ONE candidate against all
// keys (rank = # strictly greater; keys distinct via ~idx), then decodes and
// scatter-writes by rank. Slots never written are pre-zeroed by memset.
__global__ __launch_bounds__(256)
void rank_kernel(const u64* __restrict__ pool, const u32* __restrict__ cntG,
                 const float* __restrict__ anchors, const float* __restrict__ regs,
                 const int* __restrict__ imh, const int* __restrict__ imw,
                 u64* __restrict__ sortedKey, float4* __restrict__ candBox,
                 float* __restrict__ candArea) {
    __shared__ __align__(16) u64 keys[CAP];       // 16 KB
    int c = blockIdx.x, q = blockIdx.y, tid = threadIdx.x;
    int n = (int)cntG[c]; if (n > CAP) n = CAP;
    if (q * 256 >= n) return;                      // uniform: whole block idle
    for (int i = tid; i < n; i += 256) keys[i] = pool[(size_t)c * CAP + i];
    __syncthreads();
    int my = q * 256 + tid;
    u64 k0 = (my < n) ? keys[my] : ~0ull;          // sentinel: rank 0, write-guarded
    int r0 = 0;
    int j = 0;
    for (; j + 8 <= n; j += 8) {
        ulonglong2 p0 = *(const ulonglong2*)&keys[j];
        ulonglong2 p1 = *(const ulonglong2*)&keys[j + 2];
        ulonglong2 p2 = *(const ulonglong2*)&keys[j + 4];
        ulonglong2 p3 = *(const ulonglong2*)&keys[j + 6];
        r0 += (int)(p0.x > k0) + (int)(p0.y > k0)
            + (int)(p1.x > k0) + (int)(p1.y > k0)
            + (int)(p2.x > k0) + (int)(p2.y > k0)
            + (int)(p3.x > k0) + (int)(p3.y > k0);
    }
    for (; j < n; ++j) r0 += (int)(keys[j] > k0);
    if (my < n && r0 < TOPK) {
        float sc = __uint_as_float((u32)(k0 >> 32));
        int a = (int)(~(u32)k0);
        float fw = (float)(*imw), fh = (float)(*imh);
        float4 bx = make_float4(0.f, 0.f, 0.f, 0.f);
        if (sc > SCORE_THR) decode_box(anchors, regs, a, fw, fh, &bx);
        int g = c * TOPK + r0;
        sortedKey[g] = k0;
        candBox[g] = bx;
        candArea[g] = fmaxf(bx.z - bx.x, 0.0f) * fmaxf(bx.w - bx.y, 0.0f);
    }
}

// Fused IoU + greedy NMS + output, one block per class. The suppression
// bit-matrix lives ONLY in LDS (no global round trip, no copy phase).
// LDS: box 16K + area 4K + sup 128K + keep 256B = 148.3 KB -> 1 block/CU.
// Division eliminated: RN32(inter/d) > 0.5f  <=>  inter > (0.5+2^-25)*d (exact
// in double, tie unreachable for f32 operands) -> decisions bit-identical.
__global__ __launch_bounds__(1024)
void iounms_kernel(const float4* __restrict__ candBox, const float* __restrict__ candArea,
                   const u64* __restrict__ sortedKey, float* __restrict__ out) {
#pragma clang fp contract(off)
    __shared__ float4 box[TOPK];                      // 16 KB
    __shared__ float area[TOPK];                      //  4 KB
    __shared__ __align__(16) u64 supLds[TOPK * 16];   // 128 KB
    __shared__ u64 keepI[16];
    __shared__ u64 keepF[16];
    int c = blockIdx.x, tid = threadIdx.x;
    int lane = tid & 63, wave = tid >> 6;

    for (int i = tid; i < TOPK; i += 1024) {
        box[i] = candBox[(size_t)c * TOPK + i];
        area[i] = candArea[(size_t)c * TOPK + i];
    }
    u64 key = (tid < TOPK) ? sortedKey[c * TOPK + tid] : 0ull;
    float sc = __uint_as_float((u32)(key >> 32));
    bool valid = (tid < TOPK) && (sc > SCORE_THR);
    u64 mb = __ballot(valid);
    if (lane == 0) keepI[wave] = mb;
    __syncthreads();

    // IoU phase: rows striped over the 16 waves, sup words built by ballot.
    const double CC = 0.5 + 0x1p-25;
    for (int i = wave; i < TOPK; i += 16) {
        float4 bi = box[i];
        float ai = area[i];
        int jw0 = i >> 6;
        if (lane < jw0) supLds[i * 16 + lane] = 0ull;
#pragma unroll 4
        for (int jw = jw0; jw < 16; ++jw) {
            int j = (jw << 6) | lane;
            bool sup = false;
            if (j > i && j < TOPK) {
                float4 bj = box[j];
                float ltx = fmaxf(bi.x, bj.x), lty = fmaxf(bi.y, bj.y);
                float rbx = fminf(bi.z, bj.z), rby = fminf(bi.w, bj.w);
                float ww = fmaxf(rbx - ltx, 0.0f), hh = fmaxf(rby - lty, 0.0f);
                float inter = ww * hh;
                float uni = (ai + area[j]) - inter;
                float d = fmaxf(uni, 1e-8f);
                sup = (double)inter > CC * (double)d;
            }
            u64 mm = __ballot(sup);
            if (lane == 0) supLds[i * 16 + jw] = mm;
        }
    }
    __syncthreads();

    // Serial greedy pass on wave 0: readlane (SALU broadcast) in the chain,
    // 8-deep LDS prefetch pipeline.
    if (tid < 64) {
        u64 kw = (lane < 16) ? keepI[lane] : 0ull;
        u64 buf[8];
#pragma unroll
        for (int u = 0; u < 8; ++u)
            buf[u] = (lane < 16) ? supLds[u * 16 + lane] : 0ull;
        for (int i0 = 0; i0 < TOPK; i0 += 8) {
#pragma unroll
            for (int u = 0; u < 8; ++u) {
                int i = i0 + u;
                u32 wlo = (u32)__builtin_amdgcn_readlane((int)(u32)kw, i >> 6);
                u32 whi = (u32)__builtin_amdgcn_readlane((int)(u32)(kw >> 32), i >> 6);
                u32 sel = (i & 32) ? whi : wlo;
                u64 m = (u64)0 - (u64)((sel >> (i & 31)) & 1u);
                kw &= ~(buf[u] & m);
                int nx = i + 8;
                buf[u] = (nx < TOPK && lane < 16) ? supLds[nx * 16 + lane] : 0ull;
            }
        }
        if (lane < 16) keepF[lane] = kw;
    }
    __syncthreads();

    if (tid < TOPK) {
        bool keep = (keepF[tid >> 6] >> (tid & 63)) & 1ull;
        int g = c * TOPK + tid;
        out[g] = keep ? sc : 0.0f;
        out[C_NUM * TOPK + g] = keep ? (float)c : -1.0f;
        float4 b = keep ? box[tid] : make_float4(0.f, 0.f, 0.f, 0.f);
        ((float4*)(out + 2 * C_NUM * TOPK))[g] = b;
    }
}

extern "C" void kernel_launch(void* const* d_in, const int* in_sizes, int n_in,
                              void* d_out, int out_size, void* d_ws, size_t ws_size,
                              hipStream_t stream) {
    const float* cls  = (const float*)d_in[0];
    const float* reg  = (const float*)d_in[1];
    const float* anch = (const float*)d_in[2];
    const int* imh    = (const int*)d_in[3];
    const int* imw    = (const int*)d_in[4];
    int A = in_sizes[2] / 4;
    int nvec = (A * C_NUM) / 4;

    char* w = (char*)d_ws;
    size_t off = 0;
    auto alloc = [&](size_t bytes) -> void* {
        off = (off + 255) & ~(size_t)255;
        void* p = w + off;
        off += bytes;
        return p;
    };
    u32*    cntG      = (u32*)   alloc((size_t)C_NUM * 4);
    u32*    thrG      = (u32*)   alloc((size_t)C_NUM * 4);
    u32*    slices    = (u32*)   alloc((size_t)GRID_SCAN * C_NUM * HB * 4);   // 10.5 MB
    u64*    pool      = (u64*)   alloc((size_t)C_NUM * CAP * 8);              // 1.3 MB
    // contiguous zero-fill span: sortedKey + candBox + candArea
    u64*    sortedKey = (u64*)   alloc((size_t)C_NUM * TOPK * 8);
    float4* candBox   = (float4*)alloc((size_t)C_NUM * TOPK * 16);
    float*  candArea  = (float*) alloc((size_t)C_NUM * TOPK * 4);
    size_t zspan = (char*)(candArea + (size_t)C_NUM * TOPK) - (char*)sortedKey;

    hipMemsetAsync(cntG, 0, (size_t)C_NUM * 4, stream);
    hipMemsetAsync(sortedKey, 0, zspan, stream);
    hist_kernel<<<GRID_SCAN, 1024, 0, stream>>>((const float4*)cls, slices, nvec);
    thr_kernel<<<C_NUM, 1024, 0, stream>>>(slices, thrG);
    gather_kernel<<<GRID_SCAN, 1024, 0, stream>>>((const float4*)cls, thrG, cntG, pool, nvec);
    rank_kernel<<<dim3(C_NUM, 8), 256, 0, stream>>>(pool, cntG, anch, reg, imh, imw,
                                                    sortedKey, candBox, candArea);
    iounms_kernel<<<C_NUM, 1024, 0, stream>>>(candBox, candArea, sortedKey, (float*)d_out);
}

// Round 8
// 160.862 us; speedup vs baseline: 1.6932x; 1.6932x over previous
//
#include <hip/hip_runtime.h>
#include <hip/hip_bf16.h>
#include <math.h>

typedef unsigned long long u64;
typedef unsigned int u32;

#define C_NUM 80
#define TOPK 1000
#define CAP 2048
#define HB 128
#define STG 32
#define NCHUNK 16
#define SCORE_THR 0.05f
#define IOU_THR 0.5f
#define GRID_SCAN 256

// correctly-rounded-ish f32 exp via double (matched reference bit-exact rounds 1-7)
__device__ __forceinline__ float exp_cr(float x) {
    return (float)exp((double)x);
}

__device__ __forceinline__ u64 readlane64(u64 v, int l) {
    u32 lo = (u32)__builtin_amdgcn_readlane((int)(u32)v, l);
    u32 hi = (u32)__builtin_amdgcn_readlane((int)(u32)(v >> 32), l);
    return ((u64)hi << 32) | lo;
}

// Exact f32 replication of reference decode + clip (no FMA contraction).
__device__ __forceinline__ void decode_box(const float* __restrict__ anch,
                                           const float* __restrict__ reg,
                                           int a, float fw, float fh, float4* out) {
#pragma clang fp contract(off)
    float a0 = anch[(size_t)a * 4 + 0], a1 = anch[(size_t)a * 4 + 1];
    float a2 = anch[(size_t)a * 4 + 2], a3 = anch[(size_t)a * 4 + 3];
    float d0 = reg[(size_t)a * 4 + 0], d1 = reg[(size_t)a * 4 + 1];
    float d2 = reg[(size_t)a * 4 + 2], d3 = reg[(size_t)a * 4 + 3];
    float w = a2 - a0, h = a3 - a1;
    float cx = a0 + 0.5f * w, cy = a1 + 0.5f * h;
    float dx = d0 * 0.1f, dy = d1 * 0.1f, dw = d2 * 0.2f, dh = d3 * 0.2f;
    float t1 = dx * w; float pcx = cx + t1;
    float t2 = dy * h; float pcy = cy + t2;
    float pw = exp_cr(dw) * w;
    float ph = exp_cr(dh) * h;
    float x1 = pcx - 0.5f * pw, y1 = pcy - 0.5f * ph;
    float x2 = pcx + 0.5f * pw, y2 = pcy + 0.5f * ph;
    x1 = fminf(fmaxf(x1, 0.0f), fw);
    y1 = fminf(fmaxf(y1, 0.0f), fh);
    x2 = fminf(fmaxf(x2, 0.0f), fw);
    y2 = fminf(fmaxf(y2, 0.0f), fh);
    *out = make_float4(x1, y1, x2, y2);
}

// Per-block private histogram slices; no global atomics at all.
__global__ __launch_bounds__(1024)
void hist_kernel(const float4* __restrict__ cls4, u32* __restrict__ slices, int nvec) {
    __shared__ u32 h[C_NUM * HB];                 // 40 KB
    int tid = threadIdx.x;
    for (int i = tid; i < C_NUM * HB; i += 1024) h[i] = 0u;
    __syncthreads();
    int gid = blockIdx.x * 1024 + tid;
    const int stride = GRID_SCAN * 1024;          // float4 units
    const int dC = (stride * 4) % C_NUM;
    int c0 = (gid * 4) % C_NUM;
    for (int v = gid; v < nvec; v += stride) {
        float4 f = cls4[v];
        float e[4] = {f.x, f.y, f.z, f.w};
        int cc = c0;
#pragma unroll
        for (int k = 0; k < 4; ++k) {
            int t = (((int)__float_as_uint(e[k])) - 0x3F000000) >> 16;
            if (t > 0) {
                t = t > HB - 1 ? HB - 1 : t;
                atomicAdd(&h[cc * HB + t], 1u);   // LDS atomic only
            }
            cc++; if (cc == C_NUM) cc = 0;
        }
        c0 += dC; if (c0 >= C_NUM) c0 -= C_NUM;
    }
    __syncthreads();
    u32* my = slices + (size_t)blockIdx.x * (C_NUM * HB);
    for (int i = tid; i < C_NUM * HB; i += 1024) my[i] = h[i];
}

// Per-class: parallel reduce of 256 slices (8 groups x 128 buckets) -> suffix-sum
// -> threshold bit-edge.
__global__ __launch_bounds__(1024)
void thr_kernel(const u32* __restrict__ slices, u32* __restrict__ thrG) {
    __shared__ u32 part[8][HB];
    __shared__ u32 s[HB];
    __shared__ int bsel;
    int c = blockIdx.x, tid = threadIdx.x;
    int b = tid & (HB - 1), g = tid >> 7;         // 8 groups of 32 slices each
    u32 sum = 0;
    const u32* base = slices + c * HB + b;
    for (int sl = g * 32; sl < g * 32 + 32; ++sl)
        sum += base[(size_t)sl * (C_NUM * HB)];   // lanes read consecutive -> coalesced
    part[g][b] = sum;
    if (tid == 0) bsel = 0;
    __syncthreads();
    if (tid < HB) {
        u32 t = 0;
#pragma unroll
        for (int g2 = 0; g2 < 8; ++g2) t += part[g2][tid];
        s[tid] = t;
    }
    __syncthreads();
    for (int d = 1; d < HB; d <<= 1) {
        u32 v = 0;
        if (tid < HB) v = s[tid] + ((tid + d < HB) ? s[tid + d] : 0u);
        __syncthreads();
        if (tid < HB) s[tid] = v;
        __syncthreads();
    }
    if (tid < HB) {
        u32 me = s[tid];
        u32 nxt = (tid < HB - 1) ? s[tid + 1] : 0u;
        if (me >= (u32)TOPK && (tid == HB - 1 || nxt < (u32)TOPK)) bsel = tid;
    }
    __syncthreads();
    if (tid == 0) {
        int bb = bsel;
        thrG[c] = (bb == 0) ? 0u : (u32)(0x3F000000 + (bb << 16));
    }
}

// Gather with block-local LDS staging; ONE bulk reservation atomic per (class,block).
__global__ __launch_bounds__(1024)
void gather_kernel(const float4* __restrict__ cls4, const u32* __restrict__ thrG,
                   u32* __restrict__ cntG, u64* __restrict__ pool, int nvec) {
    __shared__ int thrS[C_NUM];
    __shared__ u32 lcnt[C_NUM];
    __shared__ u32 lbase[C_NUM];
    __shared__ u64 stage[C_NUM * STG];            // 20 KB
    int tid = threadIdx.x;
    if (tid < C_NUM) { thrS[tid] = (int)thrG[tid]; lcnt[tid] = 0u; }
    __syncthreads();

    int gid = blockIdx.x * 1024 + tid;
    const int stride = GRID_SCAN * 1024;
    const int dA = (stride * 4) / C_NUM;
    const int dC = (stride * 4) % C_NUM;
    int base = gid * 4;
    int aa0 = base / C_NUM;
    int c0 = base - aa0 * C_NUM;
    for (int v = gid; v < nvec; v += stride) {
        float4 f = cls4[v];
        float e[4] = {f.x, f.y, f.z, f.w};
        int cc = c0, aa = aa0;
#pragma unroll
        for (int k = 0; k < 4; ++k) {
            int bits = (int)__float_as_uint(e[k]);
            if (bits >= thrS[cc]) {
                u64 key = ((u64)(u32)bits << 32) | (u64)(u32)(~(u32)aa);
                u32 p = atomicAdd(&lcnt[cc], 1u);             // LDS atomic
                if (p < STG) stage[cc * STG + p] = key;
                else {                                         // rare overflow fallback
                    u32 q = atomicAdd(&cntG[cc], 1u);
                    if (q < CAP) pool[(size_t)cc * CAP + q] = key;
                }
            }
            cc++; if (cc == C_NUM) { cc = 0; aa++; }
        }
        c0 += dC;
        if (c0 >= C_NUM) { c0 -= C_NUM; aa0 += dA + 1; } else aa0 += dA;
    }
    __syncthreads();
    if (tid < C_NUM) {
        u32 nl = lcnt[tid]; if (nl > STG) nl = STG;
        lbase[tid] = nl ? atomicAdd(&cntG[tid], nl) : 0u;      // one atomic per class
        lcnt[tid] = nl;
    }
    __syncthreads();
    for (int i = tid; i < C_NUM * STG; i += 1024) {
        int c = i >> 5, k = i & (STG - 1);
        if ((u32)k < lcnt[c]) {
            u32 q = lbase[c] + (u32)k;
            if (q < CAP) pool[(size_t)c * CAP + q] = stage[i];
        }
    }
}

// Rank-sort spread over all CUs: grid (C_NUM, 8) x 256.
__global__ __launch_bounds__(256)
void rank_kernel(const u64* __restrict__ pool, const u32* __restrict__ cntG,
                 const float* __restrict__ anchors, const float* __restrict__ regs,
                 const int* __restrict__ imh, const int* __restrict__ imw,
                 u64* __restrict__ sortedKey, float4* __restrict__ candBox,
                 float* __restrict__ candArea) {
    __shared__ __align__(16) u64 keys[CAP];       // 16 KB
    int c = blockIdx.x, q = blockIdx.y, tid = threadIdx.x;
    int n = (int)cntG[c]; if (n > CAP) n = CAP;
    if (q * 256 >= n) return;                      // uniform: whole block idle
    for (int i = tid; i < n; i += 256) keys[i] = pool[(size_t)c * CAP + i];
    __syncthreads();
    int my = q * 256 + tid;
    u64 k0 = (my < n) ? keys[my] : ~0ull;          // sentinel: rank 0, write-guarded
    int r0 = 0;
    int j = 0;
    for (; j + 8 <= n; j += 8) {
        ulonglong2 p0 = *(const ulonglong2*)&keys[j];
        ulonglong2 p1 = *(const ulonglong2*)&keys[j + 2];
        ulonglong2 p2 = *(const ulonglong2*)&keys[j + 4];
        ulonglong2 p3 = *(const ulonglong2*)&keys[j + 6];
        r0 += (int)(p0.x > k0) + (int)(p0.y > k0)
            + (int)(p1.x > k0) + (int)(p1.y > k0)
            + (int)(p2.x > k0) + (int)(p2.y > k0)
            + (int)(p3.x > k0) + (int)(p3.y > k0);
    }
    for (; j < n; ++j) r0 += (int)(keys[j] > k0);
    if (my < n && r0 < TOPK) {
        float sc = __uint_as_float((u32)(k0 >> 32));
        int a = (int)(~(u32)k0);
        float fw = (float)(*imw), fh = (float)(*imh);
        float4 bx = make_float4(0.f, 0.f, 0.f, 0.f);
        if (sc > SCORE_THR) decode_box(anchors, regs, a, fw, fh, &bx);
        int g = c * TOPK + r0;
        sortedKey[g] = k0;
        candBox[g] = bx;
        candArea[g] = fmaxf(bx.z - bx.x, 0.0f) * fmaxf(bx.w - bx.y, 0.0f);
    }
}

// Suppression bit-matrix, TRANSPOSED store: supT[c][t][i] = 64-bit word t of row i
// (bit j-in-word set iff j>i && iou(i,j)>0.5). Distributed over all CUs.
// Lower-triangle words never written (never read downstream).
// Division eliminated: RN32(inter/d) > 0.5f  <=>  inter > (0.5+2^-25)*d (exact in
// double, tie unreachable for f32 operands) -> decisions bit-identical.
__global__ __launch_bounds__(256)
void iou_kernel(const float4* __restrict__ candBox, const float* __restrict__ candArea,
                u64* __restrict__ supT) {
#pragma clang fp contract(off)
    __shared__ float4 box[TOPK];                  // 16 KB
    __shared__ float area[TOPK];                  //  4 KB
    int c = blockIdx.x, q = blockIdx.y;
    int tid = threadIdx.x, lane = tid & 63, wave = tid >> 6;
    for (int i = tid; i < TOPK; i += 256) {
        box[i] = candBox[(size_t)c * TOPK + i];
        area[i] = candArea[(size_t)c * TOPK + i];
    }
    __syncthreads();
    const double CC = 0.5 + 0x1p-25;
    u64* colBase = supT + (size_t)c * NCHUNK * 1024;
    for (int t = wave; 16 * t + q < TOPK; t += 4) {
        int i = 16 * t + q;
        float4 bi = box[i];
        float ai = area[i];
        int jw0 = i >> 6;
#pragma unroll 4
        for (int jw = jw0; jw < NCHUNK; ++jw) {
            int j = (jw << 6) | lane;
            bool sup = false;
            if (j > i && j < TOPK) {
                float4 bj = box[j];
                float ltx = fmaxf(bi.x, bj.x), lty = fmaxf(bi.y, bj.y);
                float rbx = fminf(bi.z, bj.z), rby = fminf(bi.w, bj.w);
                float ww = fmaxf(rbx - ltx, 0.0f), hh = fmaxf(rby - lty, 0.0f);
                float inter = ww * hh;
                float uni = (ai + area[j]) - inter;
                float d = fmaxf(uni, 1e-8f);
                sup = (double)inter > CC * (double)d;
            }
            u64 mm = __ballot(sup);
            if (lane == 0) colBase[(size_t)jw * 1024 + i] = mm;
        }
    }
}

// Chunked greedy NMS + output, one block per class, NO sup-matrix copy.
// Wave t owns keep-word t (uniform u64 in registers). Per 64-row chunk w:
//   - wave w runs the intra-chunk closure: 64 fully-unrolled iterations; the
//     v_readlanes hit a loop-invariant register (chunk-w column data), so the
//     carried chain is ~4 scalar ops/iter;
//   - broadcast final keep word via LDS; one barrier;
//   - waves t>w: cross-chunk suppression = masked 64-lane OR-reduce (shfl_xor)
//     of their coalesced, prefetched column chunk.
__global__ __launch_bounds__(1024)
void nmsout_kernel(const u64* __restrict__ supT, const u64* __restrict__ sortedKey,
                   const float4* __restrict__ candBox, float* __restrict__ out) {
    __shared__ u64 km[NCHUNK];
    int c = blockIdx.x, tid = threadIdx.x;
    int lane = tid & 63, wave = tid >> 6;

    u64 key = (tid < TOPK) ? sortedKey[c * TOPK + tid] : 0ull;
    float sc = __uint_as_float((u32)(key >> 32));
    bool valid = (tid < TOPK) && (sc > SCORE_THR);
    u64 kw = __ballot(valid);                       // wave t's keep word, uniform

    const u64* col = supT + ((size_t)c * NCHUNK + wave) * 1024;
    u64 v = col[lane];                              // chunk 0 column data

    for (int w = 0; w < NCHUNK; ++w) {
        u64 v_next = 0ull;
        if (w + 1 < NCHUNK && wave >= w + 1) v_next = col[64 * (w + 1) + lane];
        if (wave == w) {
            u64 am = kw;
#pragma unroll
            for (int i = 0; i < 64; ++i) {
                u64 row = readlane64(v, i);         // loop-invariant source reg
                u64 bit = (am >> i) & 1ull;
                am &= ~(row & (0ull - bit));
            }
            kw = am;
            if (lane == 0) km[w] = am;
        }
        __syncthreads();
        if (wave > w) {
            u64 kmw = km[w];                        // uniform LDS broadcast
            u64 masked = ((kmw >> lane) & 1ull) ? v : 0ull;
            u32 mlo = (u32)masked, mhi = (u32)(masked >> 32);
#pragma unroll
            for (int s = 1; s < 64; s <<= 1) {
                mlo |= __shfl_xor(mlo, s);
                mhi |= __shfl_xor(mhi, s);
            }
            kw &= ~(((u64)mhi << 32) | mlo);
        }
        v = v_next;
    }

    if (tid < TOPK) {
        bool keep = (kw >> lane) & 1ull;
        int g = c * TOPK + tid;
        out[g] = keep ? sc : 0.0f;
        out[C_NUM * TOPK + g] = keep ? (float)c : -1.0f;
        float4 b = keep ? candBox[(size_t)c * TOPK + tid]
                        : make_float4(0.f, 0.f, 0.f, 0.f);
        ((float4*)(out + 2 * C_NUM * TOPK))[g] = b;
    }
}

extern "C" void kernel_launch(void* const* d_in, const int* in_sizes, int n_in,
                              void* d_out, int out_size, void* d_ws, size_t ws_size,
                              hipStream_t stream) {
    const float* cls  = (const float*)d_in[0];
    const float* reg  = (const float*)d_in[1];
    const float* anch = (const float*)d_in[2];
    const int* imh    = (const int*)d_in[3];
    const int* imw    = (const int*)d_in[4];
    int A = in_sizes[2] / 4;
    int nvec = (A * C_NUM) / 4;

    char* w = (char*)d_ws;
    size_t off = 0;
    auto alloc = [&](size_t bytes) -> void* {
        off = (off + 255) & ~(size_t)255;
        void* p = w + off;
        off += bytes;
        return p;
    };
    u32*    cntG      = (u32*)   alloc((size_t)C_NUM * 4);
    u32*    thrG      = (u32*)   alloc((size_t)C_NUM * 4);
    u32*    slices    = (u32*)   alloc((size_t)GRID_SCAN * C_NUM * HB * 4);   // 10.5 MB
    u64*    pool      = (u64*)   alloc((size_t)C_NUM * CAP * 8);              // 1.3 MB
    // contiguous zero-fill span: sortedKey + candBox + candArea
    u64*    sortedKey = (u64*)   alloc((size_t)C_NUM * TOPK * 8);
    float4* candBox   = (float4*)alloc((size_t)C_NUM * TOPK * 16);
    float*  candArea  = (float*) alloc((size_t)C_NUM * TOPK * 4);
    u64*    supT      = (u64*)   alloc((size_t)C_NUM * NCHUNK * 1024 * 8);    // 10.5 MB
    size_t zspan = (char*)(candArea + (size_t)C_NUM * TOPK) - (char*)sortedKey;

    hipMemsetAsync(cntG, 0, (size_t)C_NUM * 4, stream);
    hipMemsetAsync(sortedKey, 0, zspan, stream);
    hist_kernel<<<GRID_SCAN, 1024, 0, stream>>>((const float4*)cls, slices, nvec);
    thr_kernel<<<C_NUM, 1024, 0, stream>>>(slices, thrG);
    gather_kernel<<<GRID_SCAN, 1024, 0, stream>>>((const float4*)cls, thrG, cntG, pool, nvec);
    rank_kernel<<<dim3(C_NUM, 8), 256, 0, stream>>>(pool, cntG, anch, reg, imh, imw,
                                                    sortedKey, candBox, candArea);
    iou_kernel<<<dim3(C_NUM, 16), 256, 0, stream>>>(candBox, candArea, supT);
    nmsout_kernel<<<C_NUM, 1024, 0, stream>>>(supT, sortedKey, candBox, (float*)d_out);
}

// Round 9
// 151.203 us; speedup vs baseline: 1.8013x; 1.0639x over previous
//
#include <hip/hip_runtime.h>
#include <hip/hip_bf16.h>
#include <math.h>

typedef unsigned long long u64;
typedef unsigned int u32;

#define C_NUM 80
#define TOPK 1000
#define CAP 2048
#define HB 128
#define STG 32
#define NCHUNK 16
#define SCORE_THR 0.05f
#define IOU_THR 0.5f
#define GRID_SCAN 256

// correctly-rounded-ish f32 exp via double (matched reference bit-exact rounds 1-8)
__device__ __forceinline__ float exp_cr(float x) {
    return (float)exp((double)x);
}

__device__ __forceinline__ u64 readlane64(u64 v, int l) {
    u32 lo = (u32)__builtin_amdgcn_readlane((int)(u32)v, l);
    u32 hi = (u32)__builtin_amdgcn_readlane((int)(u32)(v >> 32), l);
    return ((u64)hi << 32) | lo;
}

// Exact f32 replication of reference decode + clip (no FMA contraction).
__device__ __forceinline__ void decode_box(const float* __restrict__ anch,
                                           const float* __restrict__ reg,
                                           int a, float fw, float fh, float4* out) {
#pragma clang fp contract(off)
    float a0 = anch[(size_t)a * 4 + 0], a1 = anch[(size_t)a * 4 + 1];
    float a2 = anch[(size_t)a * 4 + 2], a3 = anch[(size_t)a * 4 + 3];
    float d0 = reg[(size_t)a * 4 + 0], d1 = reg[(size_t)a * 4 + 1];
    float d2 = reg[(size_t)a * 4 + 2], d3 = reg[(size_t)a * 4 + 3];
    float w = a2 - a0, h = a3 - a1;
    float cx = a0 + 0.5f * w, cy = a1 + 0.5f * h;
    float dx = d0 * 0.1f, dy = d1 * 0.1f, dw = d2 * 0.2f, dh = d3 * 0.2f;
    float t1 = dx * w; float pcx = cx + t1;
    float t2 = dy * h; float pcy = cy + t2;
    float pw = exp_cr(dw) * w;
    float ph = exp_cr(dh) * h;
    float x1 = pcx - 0.5f * pw, y1 = pcy - 0.5f * ph;
    float x2 = pcx + 0.5f * pw, y2 = pcy + 0.5f * ph;
    x1 = fminf(fmaxf(x1, 0.0f), fw);
    y1 = fminf(fmaxf(y1, 0.0f), fh);
    x2 = fminf(fmaxf(x2, 0.0f), fw);
    y2 = fminf(fmaxf(y2, 0.0f), fh);
    *out = make_float4(x1, y1, x2, y2);
}

// Per-block private histogram slices; no global atomics at all.
__global__ __launch_bounds__(1024)
void hist_kernel(const float4* __restrict__ cls4, u32* __restrict__ slices, int nvec) {
    __shared__ u32 h[C_NUM * HB];                 // 40 KB
    int tid = threadIdx.x;
    for (int i = tid; i < C_NUM * HB; i += 1024) h[i] = 0u;
    __syncthreads();
    int gid = blockIdx.x * 1024 + tid;
    const int stride = GRID_SCAN * 1024;          // float4 units
    const int dC = (stride * 4) % C_NUM;
    int c0 = (gid * 4) % C_NUM;
    for (int v = gid; v < nvec; v += stride) {
        float4 f = cls4[v];
        float e[4] = {f.x, f.y, f.z, f.w};
        int cc = c0;
#pragma unroll
        for (int k = 0; k < 4; ++k) {
            int t = (((int)__float_as_uint(e[k])) - 0x3F000000) >> 16;
            if (t > 0) {
                t = t > HB - 1 ? HB - 1 : t;
                atomicAdd(&h[cc * HB + t], 1u);   // LDS atomic only
            }
            cc++; if (cc == C_NUM) cc = 0;
        }
        c0 += dC; if (c0 >= C_NUM) c0 -= C_NUM;
    }
    __syncthreads();
    u32* my = slices + (size_t)blockIdx.x * (C_NUM * HB);
    for (int i = tid; i < C_NUM * HB; i += 1024) my[i] = h[i];
}

// Per-class: parallel reduce of 256 slices (8 groups x 128 buckets) -> suffix-sum
// -> threshold bit-edge.
__global__ __launch_bounds__(1024)
void thr_kernel(const u32* __restrict__ slices, u32* __restrict__ thrG) {
    __shared__ u32 part[8][HB];
    __shared__ u32 s[HB];
    __shared__ int bsel;
    int c = blockIdx.x, tid = threadIdx.x;
    int b = tid & (HB - 1), g = tid >> 7;         // 8 groups of 32 slices each
    u32 sum = 0;
    const u32* base = slices + c * HB + b;
    for (int sl = g * 32; sl < g * 32 + 32; ++sl)
        sum += base[(size_t)sl * (C_NUM * HB)];   // lanes read consecutive -> coalesced
    part[g][b] = sum;
    if (tid == 0) bsel = 0;
    __syncthreads();
    if (tid < HB) {
        u32 t = 0;
#pragma unroll
        for (int g2 = 0; g2 < 8; ++g2) t += part[g2][tid];
        s[tid] = t;
    }
    __syncthreads();
    for (int d = 1; d < HB; d <<= 1) {
        u32 v = 0;
        if (tid < HB) v = s[tid] + ((tid + d < HB) ? s[tid + d] : 0u);
        __syncthreads();
        if (tid < HB) s[tid] = v;
        __syncthreads();
    }
    if (tid < HB) {
        u32 me = s[tid];
        u32 nxt = (tid < HB - 1) ? s[tid + 1] : 0u;
        if (me >= (u32)TOPK && (tid == HB - 1 || nxt < (u32)TOPK)) bsel = tid;
    }
    __syncthreads();
    if (tid == 0) {
        int bb = bsel;
        thrG[c] = (bb == 0) ? 0u : (u32)(0x3F000000 + (bb << 16));
    }
}

// Gather with block-local LDS staging; ONE bulk reservation atomic per (class,block).
__global__ __launch_bounds__(1024)
void gather_kernel(const float4* __restrict__ cls4, const u32* __restrict__ thrG,
                   u32* __restrict__ cntG, u64* __restrict__ pool, int nvec) {
    __shared__ int thrS[C_NUM];
    __shared__ u32 lcnt[C_NUM];
    __shared__ u32 lbase[C_NUM];
    __shared__ u64 stage[C_NUM * STG];            // 20 KB
    int tid = threadIdx.x;
    if (tid < C_NUM) { thrS[tid] = (int)thrG[tid]; lcnt[tid] = 0u; }
    __syncthreads();

    int gid = blockIdx.x * 1024 + tid;
    const int stride = GRID_SCAN * 1024;
    const int dA = (stride * 4) / C_NUM;
    const int dC = (stride * 4) % C_NUM;
    int base = gid * 4;
    int aa0 = base / C_NUM;
    int c0 = base - aa0 * C_NUM;
    for (int v = gid; v < nvec; v += stride) {
        float4 f = cls4[v];
        float e[4] = {f.x, f.y, f.z, f.w};
        int cc = c0, aa = aa0;
#pragma unroll
        for (int k = 0; k < 4; ++k) {
            int bits = (int)__float_as_uint(e[k]);
            if (bits >= thrS[cc]) {
                u64 key = ((u64)(u32)bits << 32) | (u64)(u32)(~(u32)aa);
                u32 p = atomicAdd(&lcnt[cc], 1u);             // LDS atomic
                if (p < STG) stage[cc * STG + p] = key;
                else {                                         // rare overflow fallback
                    u32 q = atomicAdd(&cntG[cc], 1u);
                    if (q < CAP) pool[(size_t)cc * CAP + q] = key;
                }
            }
            cc++; if (cc == C_NUM) { cc = 0; aa++; }
        }
        c0 += dC;
        if (c0 >= C_NUM) { c0 -= C_NUM; aa0 += dA + 1; } else aa0 += dA;
    }
    __syncthreads();
    if (tid < C_NUM) {
        u32 nl = lcnt[tid]; if (nl > STG) nl = STG;
        lbase[tid] = nl ? atomicAdd(&cntG[tid], nl) : 0u;      // one atomic per class
        lcnt[tid] = nl;
    }
    __syncthreads();
    for (int i = tid; i < C_NUM * STG; i += 1024) {
        int c = i >> 5, k = i & (STG - 1);
        if ((u32)k < lcnt[c]) {
            u32 q = lbase[c] + (u32)k;
            if (q < CAP) pool[(size_t)c * CAP + q] = stage[i];
        }
    }
}

// Rank-sort spread over all CUs: grid (C_NUM, 8) x 256.
__global__ __launch_bounds__(256)
void rank_kernel(const u64* __restrict__ pool, const u32* __restrict__ cntG,
                 const float* __restrict__ anchors, const float* __restrict__ regs,
                 const int* __restrict__ imh, const int* __restrict__ imw,
                 u64* __restrict__ sortedKey, float4* __restrict__ candBox,
                 float* __restrict__ candArea) {
    __shared__ __align__(16) u64 keys[CAP];       // 16 KB
    int c = blockIdx.x, q = blockIdx.y, tid = threadIdx.x;
    int n = (int)cntG[c]; if (n > CAP) n = CAP;
    if (q * 256 >= n) return;                      // uniform: whole block idle
    for (int i = tid; i < n; i += 256) keys[i] = pool[(size_t)c * CAP + i];
    __syncthreads();
    int my = q * 256 + tid;
    u64 k0 = (my < n) ? keys[my] : ~0ull;          // sentinel: rank 0, write-guarded
    int r0 = 0;
    int j = 0;
    for (; j + 8 <= n; j += 8) {
        ulonglong2 p0 = *(const ulonglong2*)&keys[j];
        ulonglong2 p1 = *(const ulonglong2*)&keys[j + 2];
        ulonglong2 p2 = *(const ulonglong2*)&keys[j + 4];
        ulonglong2 p3 = *(const ulonglong2*)&keys[j + 6];
        r0 += (int)(p0.x > k0) + (int)(p0.y > k0)
            + (int)(p1.x > k0) + (int)(p1.y > k0)
            + (int)(p2.x > k0) + (int)(p2.y > k0)
            + (int)(p3.x > k0) + (int)(p3.y > k0);
    }
    for (; j < n; ++j) r0 += (int)(keys[j] > k0);
    if (my < n && r0 < TOPK) {
        float sc = __uint_as_float((u32)(k0 >> 32));
        int a = (int)(~(u32)k0);
        float fw = (float)(*imw), fh = (float)(*imh);
        float4 bx = make_float4(0.f, 0.f, 0.f, 0.f);
        if (sc > SCORE_THR) decode_box(anchors, regs, a, fw, fh, &bx);
        int g = c * TOPK + r0;
        sortedKey[g] = k0;
        candBox[g] = bx;
        candArea[g] = fmaxf(bx.z - bx.x, 0.0f) * fmaxf(bx.w - bx.y, 0.0f);
    }
}

// Suppression bit-matrix, TRANSPOSED store: supT[c][jw][i] = 64-bit word jw of
// row i (bit j-in-word set iff j>i && iou(i,j)>0.5).
// Register-resident inner loop: each wave owns one jw column (j-boxes in 5 VGPRs,
// loaded once), iterates the block's 64-row chunk with only 2 uniform (broadcast)
// LDS reads per row. Box array zero-padded to 1024: padded boxes provably give
// sup=false (rbx=min(bi.z,0) <= ltx => ww=0 => inter=0), so no j<TOPK predicate.
// Diagonal j>i handled by a 2-shift SALU word mask. Keep-words accumulate per
// lane (vw) and store coalesced once per column.
// Division eliminated: RN32(inter/d) > 0.5f  <=>  inter > (0.5+2^-25)*d (exact in
// double, tie unreachable for f32 operands) -> decisions bit-identical.
__global__ __launch_bounds__(256)
void iou_kernel(const float4* __restrict__ candBox, const float* __restrict__ candArea,
                u64* __restrict__ supT) {
#pragma clang fp contract(off)
    __shared__ float4 box[NCHUNK * 64];           // 16 KB (padded to 1024)
    __shared__ float area[NCHUNK * 64];           //  4 KB
    int c = blockIdx.x, q = blockIdx.y;
    int tid = threadIdx.x, lane = tid & 63, wave = tid >> 6;
    for (int i = tid; i < NCHUNK * 64; i += 256) {
        if (i < TOPK) {
            box[i] = candBox[(size_t)c * TOPK + i];
            area[i] = candArea[(size_t)c * TOPK + i];
        } else {
            box[i] = make_float4(0.f, 0.f, 0.f, 0.f);
            area[i] = 0.f;
        }
    }
    __syncthreads();

    int rowBase = q << 6;
    int rowEnd = TOPK - rowBase; if (rowEnd > 64) rowEnd = 64;   // 40 for q=15
    const double CC = 0.5 + 0x1p-25;
    u64* colBase = supT + (size_t)c * (NCHUNK * 1024) + rowBase;

    for (int jw = q + wave; jw < NCHUNK; jw += 4) {
        int j = (jw << 6) | lane;
        float4 bj = box[j];                        // register-resident column
        float aj = area[j];
        u64 vw = 0ull;
#pragma unroll 8
        for (int r = 0; r < 64; ++r) {
            int i = rowBase + r;
            float4 bi = box[i];                    // uniform -> LDS broadcast
            float ai = area[i];
            float ltx = fmaxf(bi.x, bj.x), lty = fmaxf(bi.y, bj.y);
            float rbx = fminf(bi.z, bj.z), rby = fminf(bi.w, bj.w);
            float ww = fmaxf(rbx - ltx, 0.0f), hh = fmaxf(rby - lty, 0.0f);
            float inter = ww * hh;
            float uni = (ai + aj) - inter;
            float d = fmaxf(uni, 1e-8f);
            bool sup = (double)inter > CC * (double)d;
            u64 w64 = __ballot(sup);
            if (jw == q) w64 &= (((~0ull) << 1) << r);   // keep j>i only
            vw = (lane == r) ? w64 : vw;
        }
        if (lane < rowEnd) colBase[(size_t)jw * 1024 + lane] = vw;
    }
}

// Chunked greedy NMS + output, one block per class, NO sup-matrix copy.
// Wave t owns keep-word t (uniform u64 in registers). Per 64-row chunk w:
//   - wave w runs the intra-chunk closure (readlane on loop-invariant register);
//   - broadcast final keep word via LDS; one barrier;
//   - waves t>w: cross-chunk suppression = masked 64-lane OR-reduce (shfl_xor)
//     of their coalesced, prefetched column chunk.
__global__ __launch_bounds__(1024)
void nmsout_kernel(const u64* __restrict__ supT, const u64* __restrict__ sortedKey,
                   const float4* __restrict__ candBox, float* __restrict__ out) {
    __shared__ u64 km[NCHUNK];
    int c = blockIdx.x, tid = threadIdx.x;
    int lane = tid & 63, wave = tid >> 6;

    u64 key = (tid < TOPK) ? sortedKey[c * TOPK + tid] : 0ull;
    float sc = __uint_as_float((u32)(key >> 32));
    bool valid = (tid < TOPK) && (sc > SCORE_THR);
    u64 kw = __ballot(valid);                       // wave t's keep word, uniform

    const u64* col = supT + ((size_t)c * NCHUNK + wave) * 1024;
    u64 v = col[lane];                              // chunk 0 column data

    for (int w = 0; w < NCHUNK; ++w) {
        u64 v_next = 0ull;
        if (w + 1 < NCHUNK && wave >= w + 1) v_next = col[64 * (w + 1) + lane];
        if (wave == w) {
            u64 am = kw;
#pragma unroll
            for (int i = 0; i < 64; ++i) {
                u64 row = readlane64(v, i);         // loop-invariant source reg
                u64 bit = (am >> i) & 1ull;
                am &= ~(row & (0ull - bit));
            }
            kw = am;
            if (lane == 0) km[w] = am;
        }
        __syncthreads();
        if (wave > w) {
            u64 kmw = km[w];                        // uniform LDS broadcast
            u64 masked = ((kmw >> lane) & 1ull) ? v : 0ull;
            u32 mlo = (u32)masked, mhi = (u32)(masked >> 32);
#pragma unroll
            for (int s = 1; s < 64; s <<= 1) {
                mlo |= __shfl_xor(mlo, s);
                mhi |= __shfl_xor(mhi, s);
            }
            kw &= ~(((u64)mhi << 32) | mlo);
        }
        v = v_next;
    }

    if (tid < TOPK) {
        bool keep = (kw >> lane) & 1ull;
        int g = c * TOPK + tid;
        out[g] = keep ? sc : 0.0f;
        out[C_NUM * TOPK + g] = keep ? (float)c : -1.0f;
        float4 b = keep ? candBox[(size_t)c * TOPK + tid]
                        : make_float4(0.f, 0.f, 0.f, 0.f);
        ((float4*)(out + 2 * C_NUM * TOPK))[g] = b;
    }
}

extern "C" void kernel_launch(void* const* d_in, const int* in_sizes, int n_in,
                              void* d_out, int out_size, void* d_ws, size_t ws_size,
                              hipStream_t stream) {
    const float* cls  = (const float*)d_in[0];
    const float* reg  = (const float*)d_in[1];
    const float* anch = (const float*)d_in[2];
    const int* imh    = (const int*)d_in[3];
    const int* imw    = (const int*)d_in[4];
    int A = in_sizes[2] / 4;
    int nvec = (A * C_NUM) / 4;

    char* w = (char*)d_ws;
    size_t off = 0;
    auto alloc = [&](size_t bytes) -> void* {
        off = (off + 255) & ~(size_t)255;
        void* p = w + off;
        off += bytes;
        return p;
    };
    u32*    cntG      = (u32*)   alloc((size_t)C_NUM * 4);
    u32*    thrG      = (u32*)   alloc((size_t)C_NUM * 4);
    u32*    slices    = (u32*)   alloc((size_t)GRID_SCAN * C_NUM * HB * 4);   // 10.5 MB
    u64*    pool      = (u64*)   alloc((size_t)C_NUM * CAP * 8);              // 1.3 MB
    // contiguous zero-fill span: sortedKey + candBox + candArea
    u64*    sortedKey = (u64*)   alloc((size_t)C_NUM * TOPK * 8);
    float4* candBox   = (float4*)alloc((size_t)C_NUM * TOPK * 16);
    float*  candArea  = (float*) alloc((size_t)C_NUM * TOPK * 4);
    u64*    supT      = (u64*)   alloc((size_t)C_NUM * NCHUNK * 1024 * 8);    // 10.5 MB
    size_t zspan = (char*)(candArea + (size_t)C_NUM * TOPK) - (char*)sortedKey;

    hipMemsetAsync(cntG, 0, (size_t)C_NUM * 4, stream);
    hipMemsetAsync(sortedKey, 0, zspan, stream);
    hist_kernel<<<GRID_SCAN, 1024, 0, stream>>>((const float4*)cls, slices, nvec);
    thr_kernel<<<C_NUM, 1024, 0, stream>>>(slices, thrG);
    gather_kernel<<<GRID_SCAN, 1024, 0, stream>>>((const float4*)cls, thrG, cntG, pool, nvec);
    rank_kernel<<<dim3(C_NUM, 8), 256, 0, stream>>>(pool, cntG, anch, reg, imh, imw,
                                                    sortedKey, candBox, candArea);
    iou_kernel<<<dim3(C_NUM, NCHUNK), 256, 0, stream>>>(candBox, candArea, supT);
    nmsout_kernel<<<C_NUM, 1024, 0, stream>>>(supT, sortedKey, candBox, (float*)d_out);
}

// Round 10
// 149.021 us; speedup vs baseline: 1.8277x; 1.0146x over previous
//
#include <hip/hip_runtime.h>
#include <hip/hip_bf16.h>
#include <math.h>

typedef unsigned long long u64;
typedef unsigned int u32;

#define C_NUM 80
#define TOPK 1000
#define CAP 2048
#define HB 128
#define STG 32
#define NCHUNK 16
#define SCORE_THR 0.05f
#define IOU_THR 0.5f
#define GRID_SCAN 256

// correctly-rounded-ish f32 exp via double (matched reference bit-exact rounds 1-9)
__device__ __forceinline__ float exp_cr(float x) {
    return (float)exp((double)x);
}

__device__ __forceinline__ u64 readlane64(u64 v, int l) {
    u32 lo = (u32)__builtin_amdgcn_readlane((int)(u32)v, l);
    u32 hi = (u32)__builtin_amdgcn_readlane((int)(u32)(v >> 32), l);
    return ((u64)hi << 32) | lo;
}

// Exact f32 replication of reference decode + clip (no FMA contraction).
__device__ __forceinline__ void decode_box(const float* __restrict__ anch,
                                           const float* __restrict__ reg,
                                           int a, float fw, float fh, float4* out) {
#pragma clang fp contract(off)
    float a0 = anch[(size_t)a * 4 + 0], a1 = anch[(size_t)a * 4 + 1];
    float a2 = anch[(size_t)a * 4 + 2], a3 = anch[(size_t)a * 4 + 3];
    float d0 = reg[(size_t)a * 4 + 0], d1 = reg[(size_t)a * 4 + 1];
    float d2 = reg[(size_t)a * 4 + 2], d3 = reg[(size_t)a * 4 + 3];
    float w = a2 - a0, h = a3 - a1;
    float cx = a0 + 0.5f * w, cy = a1 + 0.5f * h;
    float dx = d0 * 0.1f, dy = d1 * 0.1f, dw = d2 * 0.2f, dh = d3 * 0.2f;
    float t1 = dx * w; float pcx = cx + t1;
    float t2 = dy * h; float pcy = cy + t2;
    float pw = exp_cr(dw) * w;
    float ph = exp_cr(dh) * h;
    float x1 = pcx - 0.5f * pw, y1 = pcy - 0.5f * ph;
    float x2 = pcx + 0.5f * pw, y2 = pcy + 0.5f * ph;
    x1 = fminf(fmaxf(x1, 0.0f), fw);
    y1 = fminf(fmaxf(y1, 0.0f), fh);
    x2 = fminf(fmaxf(x2, 0.0f), fw);
    y2 = fminf(fmaxf(y2, 0.0f), fh);
    *out = make_float4(x1, y1, x2, y2);
}

// Per-block private histogram slices; no global atomics at all.
__global__ __launch_bounds__(1024)
void hist_kernel(const float4* __restrict__ cls4, u32* __restrict__ slices, int nvec) {
    __shared__ u32 h[C_NUM * HB];                 // 40 KB
    int tid = threadIdx.x;
    for (int i = tid; i < C_NUM * HB; i += 1024) h[i] = 0u;
    __syncthreads();
    int gid = blockIdx.x * 1024 + tid;
    const int stride = GRID_SCAN * 1024;          // float4 units
    const int dC = (stride * 4) % C_NUM;
    int c0 = (gid * 4) % C_NUM;
    for (int v = gid; v < nvec; v += stride) {
        float4 f = cls4[v];
        float e[4] = {f.x, f.y, f.z, f.w};
        int cc = c0;
#pragma unroll
        for (int k = 0; k < 4; ++k) {
            int t = (((int)__float_as_uint(e[k])) - 0x3F000000) >> 16;
            if (t > 0) {
                t = t > HB - 1 ? HB - 1 : t;
                atomicAdd(&h[cc * HB + t], 1u);   // LDS atomic only
            }
            cc++; if (cc == C_NUM) cc = 0;
        }
        c0 += dC; if (c0 >= C_NUM) c0 -= C_NUM;
    }
    __syncthreads();
    u32* my = slices + (size_t)blockIdx.x * (C_NUM * HB);
    for (int i = tid; i < C_NUM * HB; i += 1024) my[i] = h[i];
}

// Per-class: parallel reduce of 256 slices (8 groups x 128 buckets) -> suffix-sum
// -> threshold bit-edge.
__global__ __launch_bounds__(1024)
void thr_kernel(const u32* __restrict__ slices, u32* __restrict__ thrG) {
    __shared__ u32 part[8][HB];
    __shared__ u32 s[HB];
    __shared__ int bsel;
    int c = blockIdx.x, tid = threadIdx.x;
    int b = tid & (HB - 1), g = tid >> 7;         // 8 groups of 32 slices each
    u32 sum = 0;
    const u32* base = slices + c * HB + b;
    for (int sl = g * 32; sl < g * 32 + 32; ++sl)
        sum += base[(size_t)sl * (C_NUM * HB)];   // lanes read consecutive -> coalesced
    part[g][b] = sum;
    if (tid == 0) bsel = 0;
    __syncthreads();
    if (tid < HB) {
        u32 t = 0;
#pragma unroll
        for (int g2 = 0; g2 < 8; ++g2) t += part[g2][tid];
        s[tid] = t;
    }
    __syncthreads();
    for (int d = 1; d < HB; d <<= 1) {
        u32 v = 0;
        if (tid < HB) v = s[tid] + ((tid + d < HB) ? s[tid + d] : 0u);
        __syncthreads();
        if (tid < HB) s[tid] = v;
        __syncthreads();
    }
    if (tid < HB) {
        u32 me = s[tid];
        u32 nxt = (tid < HB - 1) ? s[tid + 1] : 0u;
        if (me >= (u32)TOPK && (tid == HB - 1 || nxt < (u32)TOPK)) bsel = tid;
    }
    __syncthreads();
    if (tid == 0) {
        int bb = bsel;
        thrG[c] = (bb == 0) ? 0u : (u32)(0x3F000000 + (bb << 16));
    }
}

// Gather with block-local LDS staging; ONE bulk reservation atomic per (class,block).
__global__ __launch_bounds__(1024)
void gather_kernel(const float4* __restrict__ cls4, const u32* __restrict__ thrG,
                   u32* __restrict__ cntG, u64* __restrict__ pool, int nvec) {
    __shared__ int thrS[C_NUM];
    __shared__ u32 lcnt[C_NUM];
    __shared__ u32 lbase[C_NUM];
    __shared__ u64 stage[C_NUM * STG];            // 20 KB
    int tid = threadIdx.x;
    if (tid < C_NUM) { thrS[tid] = (int)thrG[tid]; lcnt[tid] = 0u; }
    __syncthreads();

    int gid = blockIdx.x * 1024 + tid;
    const int stride = GRID_SCAN * 1024;
    const int dA = (stride * 4) / C_NUM;
    const int dC = (stride * 4) % C_NUM;
    int base = gid * 4;
    int aa0 = base / C_NUM;
    int c0 = base - aa0 * C_NUM;
    for (int v = gid; v < nvec; v += stride) {
        float4 f = cls4[v];
        float e[4] = {f.x, f.y, f.z, f.w};
        int cc = c0, aa = aa0;
#pragma unroll
        for (int k = 0; k < 4; ++k) {
            int bits = (int)__float_as_uint(e[k]);
            if (bits >= thrS[cc]) {
                u64 key = ((u64)(u32)bits << 32) | (u64)(u32)(~(u32)aa);
                u32 p = atomicAdd(&lcnt[cc], 1u);             // LDS atomic
                if (p < STG) stage[cc * STG + p] = key;
                else {                                         // rare overflow fallback
                    u32 q = atomicAdd(&cntG[cc], 1u);
                    if (q < CAP) pool[(size_t)cc * CAP + q] = key;
                }
            }
            cc++; if (cc == C_NUM) { cc = 0; aa++; }
        }
        c0 += dC;
        if (c0 >= C_NUM) { c0 -= C_NUM; aa0 += dA + 1; } else aa0 += dA;
    }
    __syncthreads();
    if (tid < C_NUM) {
        u32 nl = lcnt[tid]; if (nl > STG) nl = STG;
        lbase[tid] = nl ? atomicAdd(&cntG[tid], nl) : 0u;      // one atomic per class
        lcnt[tid] = nl;
    }
    __syncthreads();
    for (int i = tid; i < C_NUM * STG; i += 1024) {
        int c = i >> 5, k = i & (STG - 1);
        if ((u32)k < lcnt[c]) {
            u32 q = lbase[c] + (u32)k;
            if (q < CAP) pool[(size_t)c * CAP + q] = stage[i];
        }
    }
}

// Rank-sort spread over all CUs: grid (C_NUM, 8) x 256. Also zero-fills the
// tail slots [n, TOPK) (replaces the old 2.24 MB memset launch).
__global__ __launch_bounds__(256)
void rank_kernel(const u64* __restrict__ pool, const u32* __restrict__ cntG,
                 const float* __restrict__ anchors, const float* __restrict__ regs,
                 const int* __restrict__ imh, const int* __restrict__ imw,
                 u64* __restrict__ sortedKey, float4* __restrict__ candBox,
                 float* __restrict__ candArea) {
    __shared__ __align__(16) u64 keys[CAP];       // 16 KB
    int c = blockIdx.x, q = blockIdx.y, tid = threadIdx.x;
    int n = (int)cntG[c]; if (n > CAP) n = CAP;
    int my = q * 256 + tid;
    if (my >= n && my < TOPK) {                    // tail zero-fill
        int g = c * TOPK + my;
        sortedKey[g] = 0ull;
        candBox[g] = make_float4(0.f, 0.f, 0.f, 0.f);
        candArea[g] = 0.f;
    }
    if (q * 256 >= n) return;                      // uniform: whole block done
    for (int i = tid; i < n; i += 256) keys[i] = pool[(size_t)c * CAP + i];
    __syncthreads();
    u64 k0 = (my < n) ? keys[my] : ~0ull;          // sentinel: rank 0, write-guarded
    int r0 = 0;
    int j = 0;
    for (; j + 8 <= n; j += 8) {
        ulonglong2 p0 = *(const ulonglong2*)&keys[j];
        ulonglong2 p1 = *(const ulonglong2*)&keys[j + 2];
        ulonglong2 p2 = *(const ulonglong2*)&keys[j + 4];
        ulonglong2 p3 = *(const ulonglong2*)&keys[j + 6];
        r0 += (int)(p0.x > k0) + (int)(p0.y > k0)
            + (int)(p1.x > k0) + (int)(p1.y > k0)
            + (int)(p2.x > k0) + (int)(p2.y > k0)
            + (int)(p3.x > k0) + (int)(p3.y > k0);
    }
    for (; j < n; ++j) r0 += (int)(keys[j] > k0);
    if (my < n && r0 < TOPK) {
        float sc = __uint_as_float((u32)(k0 >> 32));
        int a = (int)(~(u32)k0);
        float fw = (float)(*imw), fh = (float)(*imh);
        float4 bx = make_float4(0.f, 0.f, 0.f, 0.f);
        if (sc > SCORE_THR) decode_box(anchors, regs, a, fw, fh, &bx);
        int g = c * TOPK + r0;
        sortedKey[g] = k0;
        candBox[g] = bx;
        candArea[g] = fmaxf(bx.z - bx.x, 0.0f) * fmaxf(bx.w - bx.y, 0.0f);
    }
}

// Suppression bit-matrix, TRANSPOSED store: supT[c][jw][i] = 64-bit word jw of
// row i (bit j-in-word set iff j>i && iou(i,j)>0.5). Register-resident columns;
// only rows/cols >= rowBase staged into LDS (block q never reads below it).
// Division eliminated: RN32(inter/d) > 0.5f  <=>  inter > (0.5+2^-25)*d (exact in
// double, tie unreachable for f32 operands) -> decisions bit-identical.
__global__ __launch_bounds__(256)
void iou_kernel(const float4* __restrict__ candBox, const float* __restrict__ candArea,
                u64* __restrict__ supT) {
#pragma clang fp contract(off)
    __shared__ float4 box[NCHUNK * 64];           // 16 KB (padded to 1024)
    __shared__ float area[NCHUNK * 64];           //  4 KB
    int c = blockIdx.x, q = blockIdx.y;
    int tid = threadIdx.x, lane = tid & 63, wave = tid >> 6;
    int rowBase = q << 6;
    for (int i = rowBase + tid; i < NCHUNK * 64; i += 256) {
        if (i < TOPK) {
            box[i] = candBox[(size_t)c * TOPK + i];
            area[i] = candArea[(size_t)c * TOPK + i];
        } else {
            box[i] = make_float4(0.f, 0.f, 0.f, 0.f);
            area[i] = 0.f;
        }
    }
    __syncthreads();

    int rowEnd = TOPK - rowBase; if (rowEnd > 64) rowEnd = 64;   // 40 for q=15
    const double CC = 0.5 + 0x1p-25;
    u64* colBase = supT + (size_t)c * (NCHUNK * 1024) + rowBase;

    for (int jw = q + wave; jw < NCHUNK; jw += 4) {
        int j = (jw << 6) | lane;
        float4 bj = box[j];                        // register-resident column
        float aj = area[j];
        u64 vw = 0ull;
#pragma unroll 8
        for (int r = 0; r < 64; ++r) {
            int i = rowBase + r;
            float4 bi = box[i];                    // uniform -> LDS broadcast
            float ai = area[i];
            float ltx = fmaxf(bi.x, bj.x), lty = fmaxf(bi.y, bj.y);
            float rbx = fminf(bi.z, bj.z), rby = fminf(bi.w, bj.w);
            float ww = fmaxf(rbx - ltx, 0.0f), hh = fmaxf(rby - lty, 0.0f);
            float inter = ww * hh;
            float uni = (ai + aj) - inter;
            float d = fmaxf(uni, 1e-8f);
            bool sup = (double)inter > CC * (double)d;
            u64 w64 = __ballot(sup);
            if (jw == q) w64 &= (((~0ull) << 1) << r);   // keep j>i only
            vw = (lane == r) ? w64 : vw;
        }
        if (lane < rowEnd) colBase[(size_t)jw * 1024 + lane] = vw;
    }
}

// Chunked greedy NMS + output, one block per class. ALL column-chunk loads are
// issued upfront into registers (vv[16], static-indexed via full unroll), so the
// remote-L2/L3 latency is paid once with full MLP and no barrier sits behind an
// outstanding vmcnt. Loop body is pure SALU/shfl/LDS.
__global__ __launch_bounds__(1024)
void nmsout_kernel(const u64* __restrict__ supT, const u64* __restrict__ sortedKey,
                   const float4* __restrict__ candBox, float* __restrict__ out) {
    __shared__ u64 km[NCHUNK];
    int c = blockIdx.x, tid = threadIdx.x;
    int lane = tid & 63, wave = tid >> 6;

    u64 key = (tid < TOPK) ? sortedKey[c * TOPK + tid] : 0ull;
    float sc = __uint_as_float((u32)(key >> 32));
    bool valid = (tid < TOPK) && (sc > SCORE_THR);
    u64 kw = __ballot(valid);                       // wave t's keep word, uniform

    const u64* col = supT + ((size_t)c * NCHUNK + wave) * 1024;
    u64 vv[NCHUNK];
#pragma unroll
    for (int w = 0; w < NCHUNK; ++w)
        vv[w] = (wave >= w) ? col[(w << 6) + lane] : 0ull;   // upfront, full MLP

#pragma unroll
    for (int w = 0; w < NCHUNK; ++w) {
        if (wave == w) {
            u64 am = kw;
#pragma unroll
            for (int i = 0; i < 64; ++i) {
                u64 row = readlane64(vv[w], i);     // static reg, const lane
                u64 bit = (am >> i) & 1ull;
                am &= ~(row & (0ull - bit));
            }
            kw = am;
            if (lane == 0) km[w] = am;
        }
        __syncthreads();
        if (wave > w) {
            u64 kmw = km[w];                        // uniform LDS broadcast
            u64 masked = ((kmw >> lane) & 1ull) ? vv[w] : 0ull;
            u32 mlo = (u32)masked, mhi = (u32)(masked >> 32);
#pragma unroll
            for (int s = 1; s < 64; s <<= 1) {
                mlo |= __shfl_xor(mlo, s);
                mhi |= __shfl_xor(mhi, s);
            }
            kw &= ~(((u64)mhi << 32) | mlo);
        }
    }

    if (tid < TOPK) {
        bool keep = (kw >> lane) & 1ull;
        int g = c * TOPK + tid;
        out[g] = keep ? sc : 0.0f;
        out[C_NUM * TOPK + g] = keep ? (float)c : -1.0f;
        float4 b = keep ? candBox[(size_t)c * TOPK + tid]
                        : make_float4(0.f, 0.f, 0.f, 0.f);
        ((float4*)(out + 2 * C_NUM * TOPK))[g] = b;
    }
}

extern "C" void kernel_launch(void* const* d_in, const int* in_sizes, int n_in,
                              void* d_out, int out_size, void* d_ws, size_t ws_size,
                              hipStream_t stream) {
    const float* cls  = (const float*)d_in[0];
    const float* reg  = (const float*)d_in[1];
    const float* anch = (const float*)d_in[2];
    const int* imh    = (const int*)d_in[3];
    const int* imw    = (const int*)d_in[4];
    int A = in_sizes[2] / 4;
    int nvec = (A * C_NUM) / 4;

    char* w = (char*)d_ws;
    size_t off = 0;
    auto alloc = [&](size_t bytes) -> void* {
        off = (off + 255) & ~(size_t)255;
        void* p = w + off;
        off += bytes;
        return p;
    };
    u32*    cntG      = (u32*)   alloc((size_t)C_NUM * 4);
    u32*    thrG      = (u32*)   alloc((size_t)C_NUM * 4);
    u32*    slices    = (u32*)   alloc((size_t)GRID_SCAN * C_NUM * HB * 4);   // 10.5 MB
    u64*    pool      = (u64*)   alloc((size_t)C_NUM * CAP * 8);              // 1.3 MB
    u64*    sortedKey = (u64*)   alloc((size_t)C_NUM * TOPK * 8);
    float4* candBox   = (float4*)alloc((size_t)C_NUM * TOPK * 16);
    float*  candArea  = (float*) alloc((size_t)C_NUM * TOPK * 4);
    u64*    supT      = (u64*)   alloc((size_t)C_NUM * NCHUNK * 1024 * 8);    // 10.5 MB

    hipMemsetAsync(cntG, 0, (size_t)C_NUM * 4, stream);
    hist_kernel<<<GRID_SCAN, 1024, 0, stream>>>((const float4*)cls, slices, nvec);
    thr_kernel<<<C_NUM, 1024, 0, stream>>>(slices, thrG);
    gather_kernel<<<GRID_SCAN, 1024, 0, stream>>>((const float4*)cls, thrG, cntG, pool, nvec);
    rank_kernel<<<dim3(C_NUM, 8), 256, 0, stream>>>(pool, cntG, anch, reg, imh, imw,
                                                    sortedKey, candBox, candArea);
    iou_kernel<<<dim3(C_NUM, NCHUNK), 256, 0, stream>>>(candBox, candArea, supT);
    nmsout_kernel<<<C_NUM, 1024, 0, stream>>>(supT, sortedKey, candBox, (float*)d_out);
}